// Round 1
// baseline (160.949 us; speedup 1.0000x reference)
//
#include <hip/hip_runtime.h>
#include <cmath>

// Problem constants
namespace {
constexpr int D_    = 512;   // model dim
constexpr int ROWS  = 1024;  // S*B
constexpr int GP    = 512;   // positions per group
// workspace layout (in floats)
constexpr int WS_Q  = 0;         // q  [16][512][64]
constexpr int WS_K  = 524288;    // k
constexpr int WS_V  = 1048576;   // v
constexpr int WS_N  = 1572864;   // nq/nk/nv (3 x 524288)
constexpr int WS_AV = 3145728;   // attn_vec [S][B][512]
constexpr int WS_AO = 3670016;   // attn_out [S][B][512]
}

// ---------------------------------------------------------------------------
// Kernel 1: QKV projection GEMM (1024 x 1536 x 512) + norm + scramble-write
// out[r][c] = sum_d h[r][d] * W[c][d];  W rows: 0..511 = Wq, 512..1535 = Wkv
// epilogue: val = log1p(relu(x)) - lam[c&511], written to nbuf[which][g][p][i]
// ---------------------------------------------------------------------------
__global__ __launch_bounds__(256) void k_qkv(const float* __restrict__ hin,
    const float* __restrict__ Wq, const float* __restrict__ Wkv,
    const float* __restrict__ lam, float* __restrict__ nbuf)
{
  __shared__ float As[64][33];
  __shared__ float Bs[64][33];
  const int tid = threadIdx.x;
  const int r0 = blockIdx.y * 64;
  const int c0 = blockIdx.x * 64;
  const int ty = tid >> 4, tx = tid & 15;
  float acc[4][4] = {};
  for (int kk = 0; kk < D_; kk += 32) {
    #pragma unroll
    for (int q = 0; q < 2; ++q) {
      int idx = q * 256 + tid;
      int row = idx >> 3, kq = idx & 7;
      float4 a4 = *(const float4*)&hin[(r0 + row) * D_ + kk + kq * 4];
      As[row][kq*4+0] = a4.x; As[row][kq*4+1] = a4.y;
      As[row][kq*4+2] = a4.z; As[row][kq*4+3] = a4.w;
      int c = c0 + row;
      const float* wr = (c < 512) ? (Wq + c * D_) : (Wkv + (c - 512) * D_);
      float4 b4 = *(const float4*)&wr[kk + kq * 4];
      Bs[row][kq*4+0] = b4.x; Bs[row][kq*4+1] = b4.y;
      Bs[row][kq*4+2] = b4.z; Bs[row][kq*4+3] = b4.w;
    }
    __syncthreads();
    #pragma unroll
    for (int k = 0; k < 32; ++k) {
      float a[4], b[4];
      #pragma unroll
      for (int i = 0; i < 4; ++i) a[i] = As[ty*4+i][k];
      #pragma unroll
      for (int j = 0; j < 4; ++j) b[j] = Bs[tx*4+j][k];
      #pragma unroll
      for (int i = 0; i < 4; ++i)
        #pragma unroll
        for (int j = 0; j < 4; ++j)
          acc[i][j] = fmaf(a[i], b[j], acc[i][j]);
    }
    __syncthreads();
  }
  #pragma unroll
  for (int i = 0; i < 4; ++i) {
    int r = r0 + ty * 4 + i;
    int s = r >> 1, bb = r & 1;
    #pragma unroll
    for (int j = 0; j < 4; ++j) {
      int c = c0 + tx * 4 + j;
      float val = log1pf(fmaxf(acc[i][j], 0.f)) - lam[c & 511];
      int which = c >> 9;           // 0=q,1=k,2=v
      int jq = c & 511;
      int hh = jq >> 6, di = jq & 63;
      int gg = bb * 8 + (s >> 6);
      int pp = ((s & 63) << 3) | hh;
      nbuf[which * 524288 + ((gg << 9) + pp) * 64 + di] = val;
    }
  }
}

// ---------------------------------------------------------------------------
// Kernel 2: tropical linear: out[row][d] = max_i(in[row][i] + Wt[d][i])
// grid.x: 2048 (4 rows/block, one per wave), grid.y: tensor 0..2
// ---------------------------------------------------------------------------
__global__ __launch_bounds__(256) void k_trop(const float* __restrict__ nbuf,
    const float* __restrict__ Wqt, const float* __restrict__ Wkt,
    const float* __restrict__ Wvt, float* __restrict__ qkv)
{
  const int t = blockIdx.y;
  const float* Wt = (t == 0) ? Wqt : (t == 1) ? Wkt : Wvt;
  const float* in = nbuf + t * 524288;
  float* out = qkv + t * 524288;
  __shared__ float Wl[64][65];
  __shared__ float nl[4][64];
  const int tid = threadIdx.x;
  #pragma unroll
  for (int q = 0; q < 16; ++q) {
    int idx = q * 256 + tid;
    Wl[idx >> 6][idx & 63] = Wt[idx];
  }
  const int w = tid >> 6, lane = tid & 63;
  const int row = blockIdx.x * 4 + w;   // [0, 8192)
  nl[w][lane] = in[row * 64 + lane];
  __syncthreads();
  float m = -INFINITY;
  #pragma unroll 4
  for (int i = 0; i < 64; i += 4) {
    float4 nv = *(const float4*)&nl[w][i];
    m = fmaxf(m, nv.x + Wl[lane][i]);
    m = fmaxf(m, nv.y + Wl[lane][i + 1]);
    m = fmaxf(m, nv.z + Wl[lane][i + 2]);
    m = fmaxf(m, nv.w + Wl[lane][i + 3]);
  }
  out[row * 64 + lane] = m;
}

// ---------------------------------------------------------------------------
// Kernel 3: fused tropical attention per group g, p-tile of 32.
// score[p][c] = min_d(q-k) - max_d(q-k);  ctx[p][d] = max_c(score + v[c][d])
// epilogue: av[s=p][b2][h2*64+d] = expm1(ctx)
// ---------------------------------------------------------------------------
__global__ __launch_bounds__(256) void k_attn(const float* __restrict__ qkv,
    float* __restrict__ av)
{
  const int g = blockIdx.y;
  const int pt = blockIdx.x;
  const float* qb = qkv + WS_Q + g * GP * 64;
  const float* kb = qkv + WS_K + g * GP * 64;
  const float* vb = qkv + WS_V + g * GP * 64;
  __shared__ float qs[32][65];
  __shared__ float ks[64][65];
  __shared__ float vs[64][68];
  __shared__ float ss[32][65];
  const int tid = threadIdx.x;
  const int tp = tid >> 4, tc = tid & 15;
  #pragma unroll
  for (int q = 0; q < 2; ++q) {
    int idx4 = q * 256 + tid;
    int row = idx4 >> 4, dq = idx4 & 15;
    float4 v4 = *(const float4*)&qb[(pt * 32 + row) * 64 + dq * 4];
    qs[row][dq*4+0] = v4.x; qs[row][dq*4+1] = v4.y;
    qs[row][dq*4+2] = v4.z; qs[row][dq*4+3] = v4.w;
  }
  float ctx[2][4];
  #pragma unroll
  for (int i = 0; i < 2; ++i)
    #pragma unroll
    for (int j = 0; j < 4; ++j) ctx[i][j] = -INFINITY;

  for (int c0 = 0; c0 < GP; c0 += 64) {
    __syncthreads();   // protect ks/vs from previous phase-2 readers
    #pragma unroll
    for (int q = 0; q < 4; ++q) {
      int idx4 = q * 256 + tid;
      int row = idx4 >> 4, dq = idx4 & 15;
      float4 k4 = *(const float4*)&kb[(c0 + row) * 64 + dq * 4];
      ks[row][dq*4+0] = k4.x; ks[row][dq*4+1] = k4.y;
      ks[row][dq*4+2] = k4.z; ks[row][dq*4+3] = k4.w;
      float4 v4 = *(const float4*)&vb[(c0 + row) * 64 + dq * 4];
      vs[row][dq*4+0] = v4.x; vs[row][dq*4+1] = v4.y;
      vs[row][dq*4+2] = v4.z; vs[row][dq*4+3] = v4.w;
    }
    __syncthreads();
    // phase 1: scores for rows tp*2+{0,1}, cols tc*4+{0..3}
    float mx[2][4], mn[2][4];
    #pragma unroll
    for (int i = 0; i < 2; ++i)
      #pragma unroll
      for (int j = 0; j < 4; ++j) { mx[i][j] = -INFINITY; mn[i][j] = INFINITY; }
    #pragma unroll 4
    for (int d = 0; d < 64; ++d) {
      float qa = qs[tp*2+0][d];
      float qc = qs[tp*2+1][d];
      #pragma unroll
      for (int j = 0; j < 4; ++j) {
        float kv_ = ks[tc*4+j][d];
        float d0 = qa - kv_;
        float d1 = qc - kv_;
        mx[0][j] = fmaxf(mx[0][j], d0); mn[0][j] = fminf(mn[0][j], d0);
        mx[1][j] = fmaxf(mx[1][j], d1); mn[1][j] = fminf(mn[1][j], d1);
      }
    }
    #pragma unroll
    for (int i = 0; i < 2; ++i)
      #pragma unroll
      for (int j = 0; j < 4; ++j)
        ss[tp*2+i][tc*4+j] = mn[i][j] - mx[i][j];   // -(max-min)
    __syncthreads();
    // phase 2: ctx[i][j] (rows tp*2+i, dims tc*4+j) over this c-chunk
    #pragma unroll 4
    for (int c = 0; c < 64; ++c) {
      float sa = ss[tp*2+0][c];
      float sb = ss[tp*2+1][c];
      float4 vv = *(const float4*)&vs[c][tc*4];
      ctx[0][0] = fmaxf(ctx[0][0], sa + vv.x);
      ctx[0][1] = fmaxf(ctx[0][1], sa + vv.y);
      ctx[0][2] = fmaxf(ctx[0][2], sa + vv.z);
      ctx[0][3] = fmaxf(ctx[0][3], sa + vv.w);
      ctx[1][0] = fmaxf(ctx[1][0], sb + vv.x);
      ctx[1][1] = fmaxf(ctx[1][1], sb + vv.y);
      ctx[1][2] = fmaxf(ctx[1][2], sb + vv.z);
      ctx[1][3] = fmaxf(ctx[1][3], sb + vv.w);
    }
  }
  const int b2 = g >> 3, h2 = g & 7;
  #pragma unroll
  for (int i = 0; i < 2; ++i) {
    int p = pt * 32 + tp * 2 + i;
    #pragma unroll
    for (int j = 0; j < 4; ++j)
      av[(p * 2 + b2) * 512 + h2 * 64 + tc * 4 + j] = expm1f(ctx[i][j]);
  }
}

// ---------------------------------------------------------------------------
// Kernel 4: output GEMM (1024 x 512 x 512): ao[r][o] = sum_j av[r][j]*Wo[o][j]
// ---------------------------------------------------------------------------
__global__ __launch_bounds__(256) void k_out(const float* __restrict__ av,
    const float* __restrict__ Wo, float* __restrict__ ao)
{
  __shared__ float As[64][33];
  __shared__ float Bs[64][33];
  const int tid = threadIdx.x;
  const int r0 = blockIdx.y * 64;
  const int c0 = blockIdx.x * 64;
  const int ty = tid >> 4, tx = tid & 15;
  float acc[4][4] = {};
  for (int kk = 0; kk < 512; kk += 32) {
    #pragma unroll
    for (int q = 0; q < 2; ++q) {
      int idx = q * 256 + tid;
      int row = idx >> 3, kq = idx & 7;
      float4 a4 = *(const float4*)&av[(r0 + row) * 512 + kk + kq * 4];
      As[row][kq*4+0] = a4.x; As[row][kq*4+1] = a4.y;
      As[row][kq*4+2] = a4.z; As[row][kq*4+3] = a4.w;
      float4 b4 = *(const float4*)&Wo[(c0 + row) * 512 + kk + kq * 4];
      Bs[row][kq*4+0] = b4.x; Bs[row][kq*4+1] = b4.y;
      Bs[row][kq*4+2] = b4.z; Bs[row][kq*4+3] = b4.w;
    }
    __syncthreads();
    #pragma unroll
    for (int k = 0; k < 32; ++k) {
      float a[4], b[4];
      #pragma unroll
      for (int i = 0; i < 4; ++i) a[i] = As[ty*4+i][k];
      #pragma unroll
      for (int j = 0; j < 4; ++j) b[j] = Bs[tx*4+j][k];
      #pragma unroll
      for (int i = 0; i < 4; ++i)
        #pragma unroll
        for (int j = 0; j < 4; ++j)
          acc[i][j] = fmaf(a[i], b[j], acc[i][j]);
    }
    __syncthreads();
  }
  #pragma unroll
  for (int i = 0; i < 4; ++i)
    #pragma unroll
    for (int j = 0; j < 4; ++j)
      ao[(r0 + ty*4 + i) * 512 + c0 + tx*4 + j] = acc[i][j];
}

// ---------------------------------------------------------------------------
// Kernel 5: residual + LayerNorm per row (D=512), one block per row
// ---------------------------------------------------------------------------
__global__ __launch_bounds__(256) void k_ln(const float* __restrict__ hin,
    const float* __restrict__ ao, const float* __restrict__ gamma,
    const float* __restrict__ beta, float* __restrict__ outp)
{
  const int r = blockIdx.x;
  const int tid = threadIdx.x;
  float2 hv = *(const float2*)&hin[r * 512 + tid * 2];
  float2 a2 = *(const float2*)&ao[r * 512 + tid * 2];
  float x0 = hv.x + a2.x, x1 = hv.y + a2.y;
  float sum = x0 + x1;
  float sq = x0 * x0 + x1 * x1;
  #pragma unroll
  for (int o = 32; o > 0; o >>= 1) {
    sum += __shfl_down(sum, o);
    sq  += __shfl_down(sq, o);
  }
  __shared__ float rs[8];
  const int lane = tid & 63, w = tid >> 6;
  if (lane == 0) { rs[w] = sum; rs[4 + w] = sq; }
  __syncthreads();
  float tot   = rs[0] + rs[1] + rs[2] + rs[3];
  float totsq = rs[4] + rs[5] + rs[6] + rs[7];
  float mu  = tot * (1.f / 512.f);
  float var = totsq * (1.f / 512.f) - mu * mu;
  float rstd = rsqrtf(fmaxf(var, 0.f) + 1e-5f);
  int c0 = tid * 2;
  outp[r * 512 + c0]     = (x0 - mu) * rstd * gamma[c0]     + beta[c0];
  outp[r * 512 + c0 + 1] = (x1 - mu) * rstd * gamma[c0 + 1] + beta[c0 + 1];
}

// ---------------------------------------------------------------------------
extern "C" void kernel_launch(void* const* d_in, const int* in_sizes, int n_in,
                              void* d_out, int out_size, void* d_ws, size_t ws_size,
                              hipStream_t stream) {
  const float* hin   = (const float*)d_in[0];
  const float* Wq    = (const float*)d_in[1];
  const float* Wkv   = (const float*)d_in[2];
  const float* Wqt   = (const float*)d_in[3];
  const float* Wkt   = (const float*)d_in[4];
  const float* Wvt   = (const float*)d_in[5];
  const float* lam   = (const float*)d_in[6];
  const float* Wo    = (const float*)d_in[7];
  const float* gamma = (const float*)d_in[8];
  const float* beta  = (const float*)d_in[9];
  float* ws  = (float*)d_ws;   // needs 16 MB (4,194,304 floats)
  float* out = (float*)d_out;

  k_qkv <<<dim3(24, 16), 256, 0, stream>>>(hin, Wq, Wkv, lam, ws + WS_N);
  k_trop<<<dim3(2048, 3), 256, 0, stream>>>(ws + WS_N, Wqt, Wkt, Wvt, ws + WS_Q);
  k_attn<<<dim3(16, 16), 256, 0, stream>>>(ws, ws + WS_AV);
  k_out <<<dim3(8, 16), 256, 0, stream>>>(ws + WS_AV, Wo, ws + WS_AO);
  k_ln  <<<dim3(1024), 256, 0, stream>>>(hin, ws + WS_AO, gamma, beta, out);
}

// Round 2
// 105.147 us; speedup vs baseline: 1.5307x; 1.5307x over previous
//
#include <hip/hip_runtime.h>
#include <cmath>

typedef __attribute__((ext_vector_type(8))) __bf16 bf16x8;
typedef __attribute__((ext_vector_type(4))) float f32x4;

namespace {
constexpr int GP = 512;      // positions per group
// workspace float-offsets for qkv buffers (relative to qkvbuf base)
constexpr int WS_Q = 0;
constexpr int WS_K = 524288;
constexpr int WS_V = 1048576;
}

__device__ inline unsigned short f2bf(float x) {
  union { float f; unsigned u; } v; v.f = x;
  unsigned r = v.u + 0x7fff + ((v.u >> 16) & 1);   // round-to-nearest-even
  return (unsigned short)(r >> 16);
}

// ---------------------------------------------------------------------------
// Kernel 0: fp32 -> bf16 conversion of h, [Wq;Wkv], Wo
// flat index space: [0,524288) h | [524288,786432) Wq | [786432,1310720) Wkv
//                   | [1310720,1572864) Wo
// ---------------------------------------------------------------------------
__global__ __launch_bounds__(256) void k_conv(const float* __restrict__ h,
    const float* __restrict__ Wq, const float* __restrict__ Wkv,
    const float* __restrict__ Wo, unsigned short* __restrict__ hb,
    unsigned short* __restrict__ Wcb, unsigned short* __restrict__ Wob)
{
  int i = (blockIdx.x * 256 + threadIdx.x) * 4;
  float4 v; unsigned short* dst;
  if (i < 524288)        { v = *(const float4*)&h[i];             dst = hb  + i; }
  else if (i < 786432)   { v = *(const float4*)&Wq[i - 524288];   dst = Wcb + (i - 524288); }
  else if (i < 1310720)  { v = *(const float4*)&Wkv[i - 786432];  dst = Wcb + (i - 524288); }
  else                   { v = *(const float4*)&Wo[i - 1310720];  dst = Wob + (i - 1310720); }
  ushort4 o;
  o.x = f2bf(v.x); o.y = f2bf(v.y); o.z = f2bf(v.z); o.w = f2bf(v.w);
  *(ushort4*)dst = o;
}

// ---------------------------------------------------------------------------
// MFMA GEMM: out[r][c] = sum_k A[r][k]*B[c][k], A/B bf16 row-major [.][512]
// 64x64 tile, 4 waves (2x2 of 32x32), 2x2 16x16x32 frags per wave, BK=64.
// EPI=0: qkv epilogue (log1p(relu)-lam, scramble-write to nbuf)
// EPI=1: plain fp32 store [r][c] with row stride 512
// ---------------------------------------------------------------------------
template<int EPI>
__global__ __launch_bounds__(256) void k_gemm(const unsigned short* __restrict__ Ab,
    const unsigned short* __restrict__ Bb, const float* __restrict__ lam,
    float* __restrict__ outp)
{
  __shared__ unsigned short As[64][72];   // 144B row stride: bank-rotates by 4
  __shared__ unsigned short Bs[64][72];
  const int tid = threadIdx.x;
  const int r0 = blockIdx.y * 64, c0 = blockIdx.x * 64;
  const int w = tid >> 6, l = tid & 63;
  const int wr = (w >> 1) * 32, wc = (w & 1) * 32;
  const int srow = tid >> 3, sk8 = (tid & 7) * 8;
  f32x4 acc[2][2] = {};
  for (int kk = 0; kk < 512; kk += 64) {
    __syncthreads();
    *(int4*)&As[srow][sk8]      = *(const int4*)&Ab[(r0 + srow) * 512 + kk + sk8];
    *(int4*)&As[srow + 32][sk8] = *(const int4*)&Ab[(r0 + srow + 32) * 512 + kk + sk8];
    *(int4*)&Bs[srow][sk8]      = *(const int4*)&Bb[(c0 + srow) * 512 + kk + sk8];
    *(int4*)&Bs[srow + 32][sk8] = *(const int4*)&Bb[(c0 + srow + 32) * 512 + kk + sk8];
    __syncthreads();
    #pragma unroll
    for (int ks = 0; ks < 2; ++ks) {
      const int kc = ks * 32 + (l >> 4) * 8;
      bf16x8 a0 = *(const bf16x8*)&As[wr +      (l & 15)][kc];
      bf16x8 a1 = *(const bf16x8*)&As[wr + 16 + (l & 15)][kc];
      bf16x8 b0 = *(const bf16x8*)&Bs[wc +      (l & 15)][kc];
      bf16x8 b1 = *(const bf16x8*)&Bs[wc + 16 + (l & 15)][kc];
      acc[0][0] = __builtin_amdgcn_mfma_f32_16x16x32_bf16(a0, b0, acc[0][0], 0, 0, 0);
      acc[0][1] = __builtin_amdgcn_mfma_f32_16x16x32_bf16(a0, b1, acc[0][1], 0, 0, 0);
      acc[1][0] = __builtin_amdgcn_mfma_f32_16x16x32_bf16(a1, b0, acc[1][0], 0, 0, 0);
      acc[1][1] = __builtin_amdgcn_mfma_f32_16x16x32_bf16(a1, b1, acc[1][1], 0, 0, 0);
    }
  }
  #pragma unroll
  for (int i = 0; i < 2; ++i) {
    #pragma unroll
    for (int j = 0; j < 2; ++j) {
      #pragma unroll
      for (int r = 0; r < 4; ++r) {
        int row = r0 + wr + i * 16 + (l >> 4) * 4 + r;   // C/D: row=(l>>4)*4+reg
        int col = c0 + wc + j * 16 + (l & 15);           //      col=l&15  (m89/m91)
        float x = acc[i][j][r];
        if constexpr (EPI == 0) {
          float val = log1pf(fmaxf(x, 0.f)) - lam[col & 511];
          int which = col >> 9, jq = col & 511;
          int hh = jq >> 6, di = jq & 63;
          int s = row >> 1, bb = row & 1;
          int gg = bb * 8 + (s >> 6);
          int pp = ((s & 63) << 3) | hh;
          outp[which * 524288 + ((gg << 9) + pp) * 64 + di] = val;
        } else {
          outp[row * 512 + col] = x;
        }
      }
    }
  }
}

// ---------------------------------------------------------------------------
// Kernel 2: tropical linear: out[row][d] = max_i(in[row][i] + Wt[d][i])
// ---------------------------------------------------------------------------
__global__ __launch_bounds__(256) void k_trop(const float* __restrict__ nbuf,
    const float* __restrict__ Wqt, const float* __restrict__ Wkt,
    const float* __restrict__ Wvt, float* __restrict__ qkv)
{
  const int t = blockIdx.y;
  const float* Wt = (t == 0) ? Wqt : (t == 1) ? Wkt : Wvt;
  const float* in = nbuf + t * 524288;
  float* out = qkv + t * 524288;
  __shared__ float Wl[64][65];
  __shared__ float nl[4][64];
  const int tid = threadIdx.x;
  #pragma unroll
  for (int q = 0; q < 16; ++q) {
    int idx = q * 256 + tid;
    Wl[idx >> 6][idx & 63] = Wt[idx];
  }
  const int w = tid >> 6, lane = tid & 63;
  const int row = blockIdx.x * 4 + w;
  nl[w][lane] = in[row * 64 + lane];
  __syncthreads();
  float m = -INFINITY;
  #pragma unroll 4
  for (int i = 0; i < 64; i += 4) {
    float4 nv = *(const float4*)&nl[w][i];
    m = fmaxf(m, nv.x + Wl[lane][i]);
    m = fmaxf(m, nv.y + Wl[lane][i + 1]);
    m = fmaxf(m, nv.z + Wl[lane][i + 2]);
    m = fmaxf(m, nv.w + Wl[lane][i + 3]);
  }
  out[row * 64 + lane] = m;
}

// ---------------------------------------------------------------------------
// Kernel 3: fused tropical attention per group g, p-tile of 32.
// score[p][c] = min_d(q-k) - max_d(q-k);  ctx[p][d] = max_c(score + v[c][d])
// epilogue: avb[s=p][b2][h2*64+d] = bf16(expm1(ctx))
// ---------------------------------------------------------------------------
__global__ __launch_bounds__(256) void k_attn(const float* __restrict__ qkv,
    unsigned short* __restrict__ avb)
{
  const int g = blockIdx.y;
  const int pt = blockIdx.x;
  const float* qb = qkv + WS_Q + g * GP * 64;
  const float* kb = qkv + WS_K + g * GP * 64;
  const float* vb = qkv + WS_V + g * GP * 64;
  __shared__ float qs[32][65];
  __shared__ float ks[64][65];
  __shared__ float vs[64][68];
  __shared__ float ss[32][65];
  const int tid = threadIdx.x;
  const int tp = tid >> 4, tc = tid & 15;
  #pragma unroll
  for (int q = 0; q < 2; ++q) {
    int idx4 = q * 256 + tid;
    int row = idx4 >> 4, dq = idx4 & 15;
    float4 v4 = *(const float4*)&qb[(pt * 32 + row) * 64 + dq * 4];
    qs[row][dq*4+0] = v4.x; qs[row][dq*4+1] = v4.y;
    qs[row][dq*4+2] = v4.z; qs[row][dq*4+3] = v4.w;
  }
  float ctx[2][4];
  #pragma unroll
  for (int i = 0; i < 2; ++i)
    #pragma unroll
    for (int j = 0; j < 4; ++j) ctx[i][j] = -INFINITY;

  for (int c0 = 0; c0 < GP; c0 += 64) {
    __syncthreads();
    #pragma unroll
    for (int q = 0; q < 4; ++q) {
      int idx4 = q * 256 + tid;
      int row = idx4 >> 4, dq = idx4 & 15;
      float4 k4 = *(const float4*)&kb[(c0 + row) * 64 + dq * 4];
      ks[row][dq*4+0] = k4.x; ks[row][dq*4+1] = k4.y;
      ks[row][dq*4+2] = k4.z; ks[row][dq*4+3] = k4.w;
      float4 v4 = *(const float4*)&vb[(c0 + row) * 64 + dq * 4];
      vs[row][dq*4+0] = v4.x; vs[row][dq*4+1] = v4.y;
      vs[row][dq*4+2] = v4.z; vs[row][dq*4+3] = v4.w;
    }
    __syncthreads();
    float mx[2][4], mn[2][4];
    #pragma unroll
    for (int i = 0; i < 2; ++i)
      #pragma unroll
      for (int j = 0; j < 4; ++j) { mx[i][j] = -INFINITY; mn[i][j] = INFINITY; }
    #pragma unroll 4
    for (int d = 0; d < 64; ++d) {
      float qa = qs[tp*2+0][d];
      float qc = qs[tp*2+1][d];
      #pragma unroll
      for (int j = 0; j < 4; ++j) {
        float kv_ = ks[tc*4+j][d];
        float d0 = qa - kv_;
        float d1 = qc - kv_;
        mx[0][j] = fmaxf(mx[0][j], d0); mn[0][j] = fminf(mn[0][j], d0);
        mx[1][j] = fmaxf(mx[1][j], d1); mn[1][j] = fminf(mn[1][j], d1);
      }
    }
    #pragma unroll
    for (int i = 0; i < 2; ++i)
      #pragma unroll
      for (int j = 0; j < 4; ++j)
        ss[tp*2+i][tc*4+j] = mn[i][j] - mx[i][j];
    __syncthreads();
    #pragma unroll 4
    for (int c = 0; c < 64; ++c) {
      float sa = ss[tp*2+0][c];
      float sb = ss[tp*2+1][c];
      float4 vv = *(const float4*)&vs[c][tc*4];
      ctx[0][0] = fmaxf(ctx[0][0], sa + vv.x);
      ctx[0][1] = fmaxf(ctx[0][1], sa + vv.y);
      ctx[0][2] = fmaxf(ctx[0][2], sa + vv.z);
      ctx[0][3] = fmaxf(ctx[0][3], sa + vv.w);
      ctx[1][0] = fmaxf(ctx[1][0], sb + vv.x);
      ctx[1][1] = fmaxf(ctx[1][1], sb + vv.y);
      ctx[1][2] = fmaxf(ctx[1][2], sb + vv.z);
      ctx[1][3] = fmaxf(ctx[1][3], sb + vv.w);
    }
  }
  const int b2 = g >> 3, h2 = g & 7;
  #pragma unroll
  for (int i = 0; i < 2; ++i) {
    int p = pt * 32 + tp * 2 + i;
    ushort4 o;
    o.x = f2bf(expm1f(ctx[i][0]));
    o.y = f2bf(expm1f(ctx[i][1]));
    o.z = f2bf(expm1f(ctx[i][2]));
    o.w = f2bf(expm1f(ctx[i][3]));
    *(ushort4*)&avb[(p * 2 + b2) * 512 + h2 * 64 + tc * 4] = o;
  }
}

// ---------------------------------------------------------------------------
// Kernel 5: residual + LayerNorm per row (D=512), one block per row
// ---------------------------------------------------------------------------
__global__ __launch_bounds__(256) void k_ln(const float* __restrict__ hin,
    const float* __restrict__ ao, const float* __restrict__ gamma,
    const float* __restrict__ beta, float* __restrict__ outp)
{
  const int r = blockIdx.x;
  const int tid = threadIdx.x;
  float2 hv = *(const float2*)&hin[r * 512 + tid * 2];
  float2 a2 = *(const float2*)&ao[r * 512 + tid * 2];
  float x0 = hv.x + a2.x, x1 = hv.y + a2.y;
  float sum = x0 + x1;
  float sq = x0 * x0 + x1 * x1;
  #pragma unroll
  for (int o = 32; o > 0; o >>= 1) {
    sum += __shfl_down(sum, o);
    sq  += __shfl_down(sq, o);
  }
  __shared__ float rs[8];
  const int lane = tid & 63, w = tid >> 6;
  if (lane == 0) { rs[w] = sum; rs[4 + w] = sq; }
  __syncthreads();
  float tot   = rs[0] + rs[1] + rs[2] + rs[3];
  float totsq = rs[4] + rs[5] + rs[6] + rs[7];
  float mu  = tot * (1.f / 512.f);
  float var = totsq * (1.f / 512.f) - mu * mu;
  float rstd = rsqrtf(fmaxf(var, 0.f) + 1e-5f);
  int c0 = tid * 2;
  outp[r * 512 + c0]     = (x0 - mu) * rstd * gamma[c0]     + beta[c0];
  outp[r * 512 + c0 + 1] = (x1 - mu) * rstd * gamma[c0 + 1] + beta[c0 + 1];
}

// ---------------------------------------------------------------------------
extern "C" void kernel_launch(void* const* d_in, const int* in_sizes, int n_in,
                              void* d_out, int out_size, void* d_ws, size_t ws_size,
                              hipStream_t stream) {
  const float* hin   = (const float*)d_in[0];
  const float* Wq    = (const float*)d_in[1];
  const float* Wkv   = (const float*)d_in[2];
  const float* Wqt   = (const float*)d_in[3];
  const float* Wkt   = (const float*)d_in[4];
  const float* Wvt   = (const float*)d_in[5];
  const float* lam   = (const float*)d_in[6];
  const float* Wo    = (const float*)d_in[7];
  const float* gamma = (const float*)d_in[8];
  const float* beta  = (const float*)d_in[9];
  char* wsb = (char*)d_ws;
  // layout (bytes): [0,6M) qkv fp32 | [6M,12M) nbuf fp32 (reused: avb@6M, ao@8M)
  //                 [12M,13M) hb bf16 | [13M,14.5M) Wcb bf16 | [14.5M,15M) Wob bf16
  float*          qkvbuf = (float*)wsb;
  float*          nbuf   = (float*)(wsb + 6291456);
  unsigned short* avb    = (unsigned short*)(wsb + 6291456);
  float*          ao     = (float*)(wsb + 8388608);
  unsigned short* hb     = (unsigned short*)(wsb + 12582912);
  unsigned short* Wcb    = (unsigned short*)(wsb + 13631488);
  unsigned short* Wob    = (unsigned short*)(wsb + 15204352);
  float* out = (float*)d_out;

  k_conv   <<<dim3(1536),    256, 0, stream>>>(hin, Wq, Wkv, Wo, hb, Wcb, Wob);
  k_gemm<0><<<dim3(24, 16),  256, 0, stream>>>(hb, Wcb, lam, nbuf);
  k_trop   <<<dim3(2048, 3), 256, 0, stream>>>(nbuf, Wqt, Wkt, Wvt, qkvbuf);
  k_attn   <<<dim3(16, 16),  256, 0, stream>>>(qkvbuf, avb);
  k_gemm<1><<<dim3(8, 16),   256, 0, stream>>>(avb, Wob, nullptr, ao);
  k_ln     <<<dim3(1024),    256, 0, stream>>>(hin, ao, gamma, beta, out);
}

// Round 3
// 83.291 us; speedup vs baseline: 1.9324x; 1.2624x over previous
//
#include <hip/hip_runtime.h>
#include <cmath>

typedef __attribute__((ext_vector_type(8))) __bf16 bf16x8;
typedef __attribute__((ext_vector_type(4))) float f32x4;

namespace {
constexpr int GP = 512;      // positions per group
constexpr int WS_Q = 0;
constexpr int WS_K = 524288;
constexpr int WS_V = 1048576;
}

__device__ inline unsigned short f2bf(float x) {
  union { float f; unsigned u; } v; v.f = x;
  unsigned r = v.u + 0x7fff + ((v.u >> 16) & 1);   // round-to-nearest-even
  return (unsigned short)(r >> 16);
}

// ---------------------------------------------------------------------------
// Kernel 0: fp32 -> bf16 conversion of h, [Wq;Wkv], Wo
// ---------------------------------------------------------------------------
__global__ __launch_bounds__(256) void k_conv(const float* __restrict__ h,
    const float* __restrict__ Wq, const float* __restrict__ Wkv,
    const float* __restrict__ Wo, unsigned short* __restrict__ hb,
    unsigned short* __restrict__ Wcb, unsigned short* __restrict__ Wob)
{
  int i = (blockIdx.x * 256 + threadIdx.x) * 4;
  float4 v; unsigned short* dst;
  if (i < 524288)        { v = *(const float4*)&h[i];             dst = hb  + i; }
  else if (i < 786432)   { v = *(const float4*)&Wq[i - 524288];   dst = Wcb + (i - 524288); }
  else if (i < 1310720)  { v = *(const float4*)&Wkv[i - 786432];  dst = Wcb + (i - 524288); }
  else                   { v = *(const float4*)&Wo[i - 1310720];  dst = Wob + (i - 1310720); }
  ushort4 o;
  o.x = f2bf(v.x); o.y = f2bf(v.y); o.z = f2bf(v.z); o.w = f2bf(v.w);
  *(ushort4*)dst = o;
}

// ---------------------------------------------------------------------------
// MFMA GEMM: out[r][c] = sum_k A[r][k]*B[c][k], A/B bf16 row-major [.][512]
// EPI=0: qkv epilogue (log1p(relu)-lam, scramble-write). EPI=1: plain store.
// ---------------------------------------------------------------------------
template<int EPI>
__global__ __launch_bounds__(256) void k_gemm(const unsigned short* __restrict__ Ab,
    const unsigned short* __restrict__ Bb, const float* __restrict__ lam,
    float* __restrict__ outp)
{
  __shared__ unsigned short As[64][72];
  __shared__ unsigned short Bs[64][72];
  const int tid = threadIdx.x;
  const int r0 = blockIdx.y * 64, c0 = blockIdx.x * 64;
  const int w = tid >> 6, l = tid & 63;
  const int wr = (w >> 1) * 32, wc = (w & 1) * 32;
  const int srow = tid >> 3, sk8 = (tid & 7) * 8;
  f32x4 acc[2][2] = {};
  for (int kk = 0; kk < 512; kk += 64) {
    __syncthreads();
    *(int4*)&As[srow][sk8]      = *(const int4*)&Ab[(r0 + srow) * 512 + kk + sk8];
    *(int4*)&As[srow + 32][sk8] = *(const int4*)&Ab[(r0 + srow + 32) * 512 + kk + sk8];
    *(int4*)&Bs[srow][sk8]      = *(const int4*)&Bb[(c0 + srow) * 512 + kk + sk8];
    *(int4*)&Bs[srow + 32][sk8] = *(const int4*)&Bb[(c0 + srow + 32) * 512 + kk + sk8];
    __syncthreads();
    #pragma unroll
    for (int ks = 0; ks < 2; ++ks) {
      const int kc = ks * 32 + (l >> 4) * 8;
      bf16x8 a0 = *(const bf16x8*)&As[wr +      (l & 15)][kc];
      bf16x8 a1 = *(const bf16x8*)&As[wr + 16 + (l & 15)][kc];
      bf16x8 b0 = *(const bf16x8*)&Bs[wc +      (l & 15)][kc];
      bf16x8 b1 = *(const bf16x8*)&Bs[wc + 16 + (l & 15)][kc];
      acc[0][0] = __builtin_amdgcn_mfma_f32_16x16x32_bf16(a0, b0, acc[0][0], 0, 0, 0);
      acc[0][1] = __builtin_amdgcn_mfma_f32_16x16x32_bf16(a0, b1, acc[0][1], 0, 0, 0);
      acc[1][0] = __builtin_amdgcn_mfma_f32_16x16x32_bf16(a1, b0, acc[1][0], 0, 0, 0);
      acc[1][1] = __builtin_amdgcn_mfma_f32_16x16x32_bf16(a1, b1, acc[1][1], 0, 0, 0);
    }
  }
  #pragma unroll
  for (int i = 0; i < 2; ++i) {
    #pragma unroll
    for (int j = 0; j < 2; ++j) {
      #pragma unroll
      for (int r = 0; r < 4; ++r) {
        int row = r0 + wr + i * 16 + (l >> 4) * 4 + r;
        int col = c0 + wc + j * 16 + (l & 15);
        float x = acc[i][j][r];
        if constexpr (EPI == 0) {
          float val = log1pf(fmaxf(x, 0.f)) - lam[col & 511];
          int which = col >> 9, jq = col & 511;
          int hh = jq >> 6, di = jq & 63;
          int s = row >> 1, bb = row & 1;
          int gg = bb * 8 + (s >> 6);
          int pp = ((s & 63) << 3) | hh;
          outp[which * 524288 + ((gg << 9) + pp) * 64 + di] = val;
        } else {
          outp[row * 512 + col] = x;
        }
      }
    }
  }
}

// ---------------------------------------------------------------------------
// Kernel 2: tropical linear: out[row][d] = max_i(in[row][i] + Wt[d][i])
// 64 rows/block; W row held in 64 VGPRs per lane (lane = output dim d).
// ---------------------------------------------------------------------------
__global__ __launch_bounds__(256) void k_trop(const float* __restrict__ nbuf,
    const float* __restrict__ Wqt, const float* __restrict__ Wkt,
    const float* __restrict__ Wvt, float* __restrict__ qkv)
{
  const int t = blockIdx.y;
  const float* Wt = (t == 0) ? Wqt : (t == 1) ? Wkt : Wvt;
  const float* in = nbuf + t * 524288;
  float* out = qkv + t * 524288;
  __shared__ float Wl[64][65];
  __shared__ float nl[64][64];
  const int tid = threadIdx.x;
  const int w = tid >> 6, lane = tid & 63;
  #pragma unroll
  for (int q = 0; q < 16; ++q) {
    int idx = q * 256 + tid;
    Wl[idx >> 6][idx & 63] = Wt[idx];
  }
  // stage 64 rows of n (coalesced float4)
  #pragma unroll
  for (int q = 0; q < 4; ++q) {
    int idx = q * 256 + tid;             // float4 index
    int row = idx >> 4, c4 = idx & 15;
    *(f32x4*)&nl[row][c4 * 4] =
        *(const f32x4*)&in[(blockIdx.x * 64 + row) * 64 + c4 * 4];
  }
  __syncthreads();
  float wreg[64];
  #pragma unroll
  for (int i = 0; i < 64; ++i) wreg[i] = Wl[lane][i];   // 2-way (free) via +1 pad
  #pragma unroll 2
  for (int it = 0; it < 16; ++it) {
    int lrow = w * 16 + it;
    float m0 = -INFINITY, m1 = -INFINITY, m2 = -INFINITY, m3 = -INFINITY;
    #pragma unroll
    for (int i = 0; i < 64; i += 4) {
      f32x4 nv = *(const f32x4*)&nl[lrow][i];   // broadcast
      m0 = fmaxf(m0, nv[0] + wreg[i]);
      m1 = fmaxf(m1, nv[1] + wreg[i + 1]);
      m2 = fmaxf(m2, nv[2] + wreg[i + 2]);
      m3 = fmaxf(m3, nv[3] + wreg[i + 3]);
    }
    out[(blockIdx.x * 64 + lrow) * 64 + lane] = fmaxf(fmaxf(m0, m1), fmaxf(m2, m3));
  }
}

// ---------------------------------------------------------------------------
// Kernel 3: tropical attention, c-split 4 ways, fp32 partial ctx out.
// Thread tile: 2 rows (tr) x 4 cols {tc+16m} phase1; 2 rows x 4 dims phase2.
// All LDS reads are b128; qs/ks/vs XOR-swizzled (blk ^= row&7).
// ---------------------------------------------------------------------------
__global__ __launch_bounds__(256) void k_attn(const float* __restrict__ qkv,
    float* __restrict__ ctxp)
{
  const int pt = blockIdx.x;        // 0..15 p-tile
  const int g  = blockIdx.y;        // 0..15 group
  const int cs = blockIdx.z;        // 0..3  c-split
  const float* qb = qkv + WS_Q + g * GP * 64;
  const float* kb = qkv + WS_K + g * GP * 64;
  const float* vb = qkv + WS_V + g * GP * 64;
  __shared__ float qs[32][64];
  __shared__ float ks[64][64];
  __shared__ float vs[64][64];
  __shared__ float ss[32][68];
  const int tid = threadIdx.x;
  const int tr = tid >> 4, tc = tid & 15;
  const int xb = tc & 7;
  // stage Q (swizzled blocks)
  #pragma unroll
  for (int q2 = 0; q2 < 2; ++q2) {
    int row = tr + q2 * 16;
    f32x4 v4 = *(const f32x4*)&qb[(pt * 32 + row) * 64 + tc * 4];
    *(f32x4*)&qs[row][((tc ^ (row & 7))) * 4] = v4;
  }
  float ctx[2][4];
  #pragma unroll
  for (int i = 0; i < 2; ++i)
    #pragma unroll
    for (int j = 0; j < 4; ++j) ctx[i][j] = -INFINITY;

  for (int cc = 0; cc < 2; ++cc) {
    const int c0 = cs * 128 + cc * 64;
    __syncthreads();
    #pragma unroll
    for (int q4 = 0; q4 < 4; ++q4) {
      int row = tr + q4 * 16;
      int sb = (tc ^ (row & 7)) * 4;
      *(f32x4*)&ks[row][sb] = *(const f32x4*)&kb[(c0 + row) * 64 + tc * 4];
      *(f32x4*)&vs[row][sb] = *(const f32x4*)&vb[(c0 + row) * 64 + tc * 4];
    }
    __syncthreads();
    // phase 1: scores for rows {2tr,2tr+1} x cols {tc+16m}
    float mx[2][4], mn[2][4];
    #pragma unroll
    for (int i = 0; i < 2; ++i)
      #pragma unroll
      for (int m = 0; m < 4; ++m) { mx[i][m] = -INFINITY; mn[i][m] = INFINITY; }
    const int r0 = tr * 2, r1 = r0 + 1;
    #pragma unroll 2
    for (int b = 0; b < 16; ++b) {
      f32x4 q0 = *(const f32x4*)&qs[r0][(b ^ (r0 & 7)) * 4];
      f32x4 q1 = *(const f32x4*)&qs[r1][(b ^ (r1 & 7)) * 4];
      const int kblk = (b ^ xb) * 4;
      #pragma unroll
      for (int m = 0; m < 4; ++m) {
        f32x4 kv = *(const f32x4*)&ks[tc + m * 16][kblk];
        #pragma unroll
        for (int e = 0; e < 4; ++e) {
          float d0 = q0[e] - kv[e];
          float d1 = q1[e] - kv[e];
          mx[0][m] = fmaxf(mx[0][m], d0); mn[0][m] = fminf(mn[0][m], d0);
          mx[1][m] = fmaxf(mx[1][m], d1); mn[1][m] = fminf(mn[1][m], d1);
        }
      }
    }
    #pragma unroll
    for (int i = 0; i < 2; ++i)
      #pragma unroll
      for (int m = 0; m < 4; ++m)
        ss[tr * 2 + i][tc + m * 16] = mn[i][m] - mx[i][m];
    __syncthreads();
    // phase 2: ctx[i][j] over this c-chunk; dims = tc*4+j
    #pragma unroll 2
    for (int cb = 0; cb < 16; ++cb) {
      f32x4 s0 = *(const f32x4*)&ss[r0][cb * 4];
      f32x4 s1 = *(const f32x4*)&ss[r1][cb * 4];
      #pragma unroll
      for (int e = 0; e < 4; ++e) {
        int c = cb * 4 + e;
        f32x4 vv = *(const f32x4*)&vs[c][(tc ^ (c & 7)) * 4];
        #pragma unroll
        for (int j = 0; j < 4; ++j) {
          ctx[0][j] = fmaxf(ctx[0][j], s0[e] + vv[j]);
          ctx[1][j] = fmaxf(ctx[1][j], s1[e] + vv[j]);
        }
      }
    }
  }
  // write fp32 partials: ctxp[cs][g][p][d]
  int base = cs * 524288 + g * 32768 + (pt * 32 + tr * 2) * 64 + tc * 4;
  f32x4 o0, o1;
  #pragma unroll
  for (int j = 0; j < 4; ++j) { o0[j] = ctx[0][j]; o1[j] = ctx[1][j]; }
  *(f32x4*)&ctxp[base]      = o0;
  *(f32x4*)&ctxp[base + 64] = o1;
}

// ---------------------------------------------------------------------------
// Kernel 4: combine 4 c-split partials: max, expm1, bf16, unscramble-write
// ---------------------------------------------------------------------------
__global__ __launch_bounds__(256) void k_comb(const float* __restrict__ ctxp,
    unsigned short* __restrict__ avb)
{
  int idx = blockIdx.x * 256 + threadIdx.x;   // 131072 float4s
  int dblk = idx & 15, p = (idx >> 4) & 511, g = idx >> 13;
  const float* cp = ctxp + g * 32768 + p * 64 + dblk * 4;
  f32x4 a = *(const f32x4*)cp;
  f32x4 b = *(const f32x4*)(cp + 524288);
  f32x4 c = *(const f32x4*)(cp + 1048576);
  f32x4 d = *(const f32x4*)(cp + 1572864);
  ushort4 o;
  float v0 = fmaxf(fmaxf(a[0], b[0]), fmaxf(c[0], d[0]));
  float v1 = fmaxf(fmaxf(a[1], b[1]), fmaxf(c[1], d[1]));
  float v2 = fmaxf(fmaxf(a[2], b[2]), fmaxf(c[2], d[2]));
  float v3 = fmaxf(fmaxf(a[3], b[3]), fmaxf(c[3], d[3]));
  o.x = f2bf(expm1f(v0)); o.y = f2bf(expm1f(v1));
  o.z = f2bf(expm1f(v2)); o.w = f2bf(expm1f(v3));
  *(ushort4*)&avb[(p * 2 + (g >> 3)) * 512 + (g & 7) * 64 + dblk * 4] = o;
}

// ---------------------------------------------------------------------------
// Kernel 5: residual + LayerNorm per row (D=512), one block per row
// ---------------------------------------------------------------------------
__global__ __launch_bounds__(256) void k_ln(const float* __restrict__ hin,
    const float* __restrict__ ao, const float* __restrict__ gamma,
    const float* __restrict__ beta, float* __restrict__ outp)
{
  const int r = blockIdx.x;
  const int tid = threadIdx.x;
  float2 hv = *(const float2*)&hin[r * 512 + tid * 2];
  float2 a2 = *(const float2*)&ao[r * 512 + tid * 2];
  float x0 = hv.x + a2.x, x1 = hv.y + a2.y;
  float sum = x0 + x1;
  float sq = x0 * x0 + x1 * x1;
  #pragma unroll
  for (int o = 32; o > 0; o >>= 1) {
    sum += __shfl_down(sum, o);
    sq  += __shfl_down(sq, o);
  }
  __shared__ float rs[8];
  const int lane = tid & 63, w = tid >> 6;
  if (lane == 0) { rs[w] = sum; rs[4 + w] = sq; }
  __syncthreads();
  float tot   = rs[0] + rs[1] + rs[2] + rs[3];
  float totsq = rs[4] + rs[5] + rs[6] + rs[7];
  float mu  = tot * (1.f / 512.f);
  float var = totsq * (1.f / 512.f) - mu * mu;
  float rstd = rsqrtf(fmaxf(var, 0.f) + 1e-5f);
  int c0 = tid * 2;
  outp[r * 512 + c0]     = (x0 - mu) * rstd * gamma[c0]     + beta[c0];
  outp[r * 512 + c0 + 1] = (x1 - mu) * rstd * gamma[c0 + 1] + beta[c0 + 1];
}

// ---------------------------------------------------------------------------
extern "C" void kernel_launch(void* const* d_in, const int* in_sizes, int n_in,
                              void* d_out, int out_size, void* d_ws, size_t ws_size,
                              hipStream_t stream) {
  const float* hin   = (const float*)d_in[0];
  const float* Wq    = (const float*)d_in[1];
  const float* Wkv   = (const float*)d_in[2];
  const float* Wqt   = (const float*)d_in[3];
  const float* Wkt   = (const float*)d_in[4];
  const float* Wvt   = (const float*)d_in[5];
  const float* lam   = (const float*)d_in[6];
  const float* Wo    = (const float*)d_in[7];
  const float* gamma = (const float*)d_in[8];
  const float* beta  = (const float*)d_in[9];
  char* wsb = (char*)d_ws;
  // byte layout:
  //  [0,6M)      qkvbuf fp32 (q|k|v)         — dead after k_attn; avb reuses [0,1M)
  //  [6M,12M)    nbuf fp32                   — dead after k_trop
  //  [6M,14M)    ctxp fp32 (4 x 2MB)         — written k_attn, read k_comb
  //  [6M,8M)     ao fp32                     — written k_gemm<1> (ctxp dead)
  //  [12M,13M)   hb bf16   — dead after gemm0 (clobbered by ctxp)
  //  [13M,14.5M) Wcb bf16  — dead after gemm0 (partially clobbered by ctxp)
  //  [14.5M,15M) Wob bf16  — survives (ctxp ends at 14M)
  float*          qkvbuf = (float*)wsb;
  float*          nbuf   = (float*)(wsb + 6291456);
  float*          ctxp   = (float*)(wsb + 6291456);
  float*          ao     = (float*)(wsb + 6291456);
  unsigned short* avb    = (unsigned short*)wsb;
  unsigned short* hb     = (unsigned short*)(wsb + 12582912);
  unsigned short* Wcb    = (unsigned short*)(wsb + 13631488);
  unsigned short* Wob    = (unsigned short*)(wsb + 15204352);
  float* out = (float*)d_out;

  k_conv   <<<dim3(1536),       256, 0, stream>>>(hin, Wq, Wkv, Wo, hb, Wcb, Wob);
  k_gemm<0><<<dim3(24, 16),     256, 0, stream>>>(hb, Wcb, lam, nbuf);
  k_trop   <<<dim3(128, 3),     256, 0, stream>>>(nbuf, Wqt, Wkt, Wvt, qkvbuf);
  k_attn   <<<dim3(16, 16, 4),  256, 0, stream>>>(qkvbuf, ctxp);
  k_comb   <<<dim3(512),        256, 0, stream>>>(ctxp, avb);
  k_gemm<1><<<dim3(8, 16),      256, 0, stream>>>(avb, Wob, nullptr, ao);
  k_ln     <<<dim3(1024),       256, 0, stream>>>(hin, ao, gamma, beta, out);
}